// Round 11
// baseline (136.537 us; speedup 1.0000x reference)
//
#include <hip/hip_runtime.h>

// B=32, C=8, L=2048, K=512, S=64, W=1985
// out[b,0,q] = max(0, max_w sum_c dot(xw_n[b,c,w,:], sn_n[c,q,:]) / 8)

#define B_ 32
#define C_ 8
#define L_ 2048
#define K_ 512
#define S_ 64
#define W_ 1985
#define LP 2176                       // padded f16 row stride (zero tail)

typedef _Float16 f16x8 __attribute__((ext_vector_type(8)));
typedef _Float16 f16x8u __attribute__((ext_vector_type(8), aligned(4)));
typedef float f32x16 __attribute__((ext_vector_type(16)));

// ---- prologue ----
// blocks 0..127:   pack shapelets in 32x32x16 B-frag layout
// blocks 128..383: f16 parity-dual x copies (xh0[p]=x[p], xh1[p]=x[p+1]) with
//                  zero-padded rows (stride LP), f16 window inv-norms, zero out
__global__ __launch_bounds__(256)
void prep_k(const float* __restrict__ x, const float* __restrict__ sh,
            _Float16* __restrict__ Bp, _Float16* __restrict__ xh0,
            _Float16* __restrict__ xh1, _Float16* __restrict__ invh,
            float* __restrict__ out) {
    __shared__ float xr[L_];             // norm blocks only
    const int tid = threadIdx.x;
    const int blk = blockIdx.x;

    if (blk < 128) {
        const int sb   = blk * 4 + (tid >> 6);   // 0..511 = c(8) x kq(4) x nt(16)
        const int c    = sb >> 6;
        const int kq   = (sb >> 4) & 3;
        const int nt   = sb & 15;
        const int lane = tid & 63;
        const int half = lane >> 5;
        const int q    = nt * 32 + (lane & 31);

        const float4* sp = (const float4*)(sh + (size_t)(c * K_ + q) * S_);
        float ss = 0.f;
        #pragma unroll
        for (int i = 0; i < 8; ++i) {
            float4 v = sp[half * 8 + i];
            ss += v.x * v.x + v.y * v.y + v.z * v.z + v.w * v.w;
        }
        ss += __shfl_xor(ss, 32);
        float inv = 1.f / fmaxf(sqrtf(ss), 1e-8f);

        float4 u0 = sp[kq * 4 + half * 2];
        float4 u1 = sp[kq * 4 + half * 2 + 1];
        f16x8 o;
        o[0] = (_Float16)(u0.x * inv); o[1] = (_Float16)(u0.y * inv);
        o[2] = (_Float16)(u0.z * inv); o[3] = (_Float16)(u0.w * inv);
        o[4] = (_Float16)(u1.x * inv); o[5] = (_Float16)(u1.y * inv);
        o[6] = (_Float16)(u1.z * inv); o[7] = (_Float16)(u1.w * inv);
        ((f16x8*)Bp)[((c * 4 + kq) * 16 + nt) * 64 + lane] = o;
    } else {
        const int r = blk - 128;             // row = b*8 + c, 0..255
        const float* xp = x + (size_t)r * L_;
        for (int i = tid; i < L_ / 4; i += 256)
            ((float4*)xr)[i] = ((const float4*)xp)[i];
        __syncthreads();

        // f16 parity-dual copies (stride LP)
        {
            const int i = tid * 8;
            f16x8 a, bsh;
            #pragma unroll
            for (int j = 0; j < 8; ++j) {
                a[j]   = (_Float16)xr[i + j];
                int n  = i + j + 1;
                bsh[j] = (_Float16)(n < L_ ? xr[n] : 0.f);
            }
            *(f16x8*)(xh0 + (size_t)r * LP + i) = a;
            *(f16x8*)(xh1 + (size_t)r * LP + i) = bsh;
        }
        // zero the row pads [L_, LP)
        if (tid < 16) {
            f16x8 z;
            #pragma unroll
            for (int j = 0; j < 8; ++j) z[j] = (_Float16)0.f;
            *(f16x8*)(xh0  + (size_t)r * LP + L_ + tid * 8) = z;
            *(f16x8*)(xh1  + (size_t)r * LP + L_ + tid * 8) = z;
            *(f16x8*)(invh + (size_t)r * LP + L_ + tid * 8) = z;
        }

        // window inverse norms via sliding sum -> f16 (stride LP)
        _Float16* ivp = invh + (size_t)r * LP;
        const int w0 = tid * 8;
        float ss = 0.f;
        if (w0 < W_) {
            #pragma unroll
            for (int j = 0; j < S_; ++j) { float v = xr[w0 + j]; ss += v * v; }
        }
        #pragma unroll
        for (int u = 0; u < 8; ++u) {
            int w = w0 + u;
            float o = 0.f;
            if (u > 0 && w < W_)
                ss += xr[w + 63] * xr[w + 63] - xr[w - 1] * xr[w - 1];
            if (w < W_) o = 0.125f / fmaxf(sqrtf(ss), 1e-8f);
            if (w < L_) ivp[w] = (_Float16)o;
        }
        if (r < 64) out[r * 256 + tid] = 0.f;   // zero output
    }
}

// ---- main: B-register-resident streaming MFMA + relu + max ----
// grid (4 mh, 4 kg, 32 b) = 512 blocks (2/CU), 256 threads = 4 waves.
// Wave: 32 cols (colg = kg*4+wv) x FULL K=512, B held in 128 VGPRs the whole
// kernel; loops 8 window-tiles of 64. Per step: 2 A loads (L1-hot) + 2 MFMAs.
// A ring: 8 slots, prefetch distance 3 (slot period 4 -> 3 mod 4 != 0, no
// collision; consume slot (2f)&7, write (2f+6)&7).
struct IvT { _Float16 v[8][2]; };

__global__ __launch_bounds__(256, 2)
void mcs_k(const _Float16* __restrict__ Bp, const _Float16* __restrict__ xh0,
           const _Float16* __restrict__ xh1, const _Float16* __restrict__ invh,
           float* __restrict__ out) {
    const int mh  = blockIdx.x;          // window quarter (512 windows)
    const int kg  = blockIdx.y;          // col group-of-128
    const int b   = blockIdx.z;
    const int tid = threadIdx.x;
    const int lane = tid & 63;
    const int wv   = tid >> 6;
    const int colg = kg * 4 + wv;        // col group-of-32
    const int l31  = lane & 31;
    const int lh   = lane >> 5;
    const int par  = l31 & 1;
    const int W0   = mh * 512;

    const _Float16* xb  = (par ? xh1 - 1 : xh0) + (size_t)(b * C_) * LP;
    const _Float16* ivb = invh + (size_t)(b * C_) * LP;

    // B: full-K register-resident (32 frags = 128 VGPRs)
    f16x8 Breg[32];
    {
        const f16x8* Bq = (const f16x8*)Bp + colg * 64 + lane;
        #pragma unroll
        for (int s = 0; s < 32; ++s) Breg[s] = Bq[s * 16 * 64];
    }

    f16x8u Ar[8];           // A-frag ring, prefetch distance 3
    auto issueA = [&](int t, int s, int mt, int slot) {
        int c = s >> 2, ks = s & 3;
        int p = W0 + t * 64 + mt * 32 + l31 + ks * 16 + lh * 8;  // pad-safe
        Ar[slot] = *(const f16x8u*)(xb + c * LP + p);
    };
    auto loadIv = [&](int t) -> IvT {
        IvT r;
        int tc = t < 8 ? t : 0;          // tile-8 prefetch: dummy valid addr
        #pragma unroll
        for (int c = 0; c < 8; ++c) {
            r.v[c][0] = ivb[c * LP + W0 + tc * 64 + l31];
            r.v[c][1] = ivb[c * LP + W0 + tc * 64 + 32 + l31];
        }
        return r;
    };

    // prolog: fill ring with flat steps 0..2 of tile 0; iv for tile 0
    #pragma unroll
    for (int s = 0; s < 3; ++s) { issueA(0, s, 0, (s * 2) & 7); issueA(0, s, 1, (s * 2 + 1) & 7); }
    IvT ivA = loadIv(0), ivB;

    float mx = 0.f;
    f32x16 acc0, acc1;

    #pragma unroll 1
    for (int tp = 0; tp < 4; ++tp) {
        #pragma unroll
        for (int hf = 0; hf < 2; ++hf) {
            const int t = tp * 2 + hf;
            #pragma unroll
            for (int r = 0; r < 16; ++r) { acc0[r] = 0.f; acc1[r] = 0.f; }
            #pragma unroll
            for (int s = 0; s < 32; ++s) {
                int ps = s + 3;                       // prefetch 3 steps ahead
                int pt = t + (ps >> 5), pss = ps & 31;  // t=7 tail -> pad, safe
                issueA(pt, pss, 0, (ps * 2) & 7);
                issueA(pt, pss, 1, (ps * 2 + 1) & 7);
                if (s == 8) { if (hf) ivA = loadIv(t + 1); else ivB = loadIv(t + 1); }
                const IvT& iv = hf ? ivB : ivA;
                int c = s >> 2;
                f16x8 af0 = (f16x8)Ar[(s * 2) & 7] * iv.v[c][0];
                f16x8 af1 = (f16x8)Ar[(s * 2 + 1) & 7] * iv.v[c][1];
                acc0 = __builtin_amdgcn_mfma_f32_32x32x16_f16(af0, Breg[s], acc0, 0, 0, 0);
                acc1 = __builtin_amdgcn_mfma_f32_32x32x16_f16(af1, Breg[s], acc1, 0, 0, 0);
            }
            // fold tile max (relu floor 0; invalid windows exactly 0)
            #pragma unroll
            for (int r = 0; r < 16; ++r) mx = fmaxf(mx, fmaxf(acc0[r], acc1[r]));
        }
    }

    // 32x32 C/D: col = lane&31; lane and lane^32 hold different window rows
    mx = fmaxf(mx, __shfl_xor(mx, 32));
    if (lane < 32)
        atomicMax((unsigned int*)(out + b * K_ + colg * 32 + l31),
                  __float_as_uint(mx));
}

extern "C" void kernel_launch(void* const* d_in, const int* in_sizes, int n_in,
                              void* d_out, int out_size, void* d_ws, size_t ws_size,
                              hipStream_t stream) {
    const float* x  = (const float*)d_in[0];   // (32, 8, 2048) fp32
    const float* sh = (const float*)d_in[1];   // (8, 512, 64) fp32
    float* out = (float*)d_out;                // (32, 1, 512) fp32

    char* ws = (char*)d_ws;
    const size_t xhN = (size_t)B_ * C_ * LP * sizeof(_Float16);  // 1.09 MB
    _Float16* Bp   = (_Float16*)ws;                              // 512 KB
    _Float16* xh0  = (_Float16*)(ws + (512 << 10));
    _Float16* xh1  = (_Float16*)(ws + (512 << 10) + xhN);
    _Float16* invh = (_Float16*)(ws + (512 << 10) + 2 * xhN);

    prep_k<<<dim3(384), dim3(256), 0, stream>>>(x, sh, Bp, xh0, xh1, invh, out);
    mcs_k<<<dim3(4, 4, B_), dim3(256), 0, stream>>>(Bp, xh0, xh1, invh, out);
}

// Round 12
// 117.630 us; speedup vs baseline: 1.1607x; 1.1607x over previous
//
#include <hip/hip_runtime.h>

// B=32, C=8, L=2048, K=512, S=64, W=1985
// out[b,0,q] = max(0, max_w sum_c dot(xw_n[b,c,w,:], sn_n[c,q,:]) / 8)

#define B_ 32
#define C_ 8
#define L_ 2048
#define K_ 512
#define S_ 64
#define W_ 1985
#define LP 2176                       // padded f16 row stride (zero tail)

typedef _Float16 f16x8 __attribute__((ext_vector_type(8)));
typedef _Float16 f16x8u __attribute__((ext_vector_type(8), aligned(4)));
typedef float f32x16 __attribute__((ext_vector_type(16)));

// ---- prologue ----
// blocks 0..127:   pack shapelets in 32x32x16 B-frag layout
// blocks 128..383: f16 parity-dual x copies (xh0[p]=x[p], xh1[p]=x[p+1]) with
//                  zero-padded rows (stride LP), f16 window inv-norms, zero out
__global__ __launch_bounds__(256)
void prep_k(const float* __restrict__ x, const float* __restrict__ sh,
            _Float16* __restrict__ Bp, _Float16* __restrict__ xh0,
            _Float16* __restrict__ xh1, _Float16* __restrict__ invh,
            float* __restrict__ out) {
    __shared__ float xr[L_];             // norm blocks only
    const int tid = threadIdx.x;
    const int blk = blockIdx.x;

    if (blk < 128) {
        const int sb   = blk * 4 + (tid >> 6);   // 0..511 = c(8) x kq(4) x nt(16)
        const int c    = sb >> 6;
        const int kq   = (sb >> 4) & 3;
        const int nt   = sb & 15;
        const int lane = tid & 63;
        const int half = lane >> 5;
        const int q    = nt * 32 + (lane & 31);

        const float4* sp = (const float4*)(sh + (size_t)(c * K_ + q) * S_);
        float ss = 0.f;
        #pragma unroll
        for (int i = 0; i < 8; ++i) {
            float4 v = sp[half * 8 + i];
            ss += v.x * v.x + v.y * v.y + v.z * v.z + v.w * v.w;
        }
        ss += __shfl_xor(ss, 32);
        float inv = 1.f / fmaxf(sqrtf(ss), 1e-8f);

        float4 u0 = sp[kq * 4 + half * 2];
        float4 u1 = sp[kq * 4 + half * 2 + 1];
        f16x8 o;
        o[0] = (_Float16)(u0.x * inv); o[1] = (_Float16)(u0.y * inv);
        o[2] = (_Float16)(u0.z * inv); o[3] = (_Float16)(u0.w * inv);
        o[4] = (_Float16)(u1.x * inv); o[5] = (_Float16)(u1.y * inv);
        o[6] = (_Float16)(u1.z * inv); o[7] = (_Float16)(u1.w * inv);
        ((f16x8*)Bp)[((c * 4 + kq) * 16 + nt) * 64 + lane] = o;
    } else {
        const int r = blk - 128;             // row = b*8 + c, 0..255
        const float* xp = x + (size_t)r * L_;
        for (int i = tid; i < L_ / 4; i += 256)
            ((float4*)xr)[i] = ((const float4*)xp)[i];
        __syncthreads();

        // f16 parity-dual copies (stride LP)
        {
            const int i = tid * 8;
            f16x8 a, bsh;
            #pragma unroll
            for (int j = 0; j < 8; ++j) {
                a[j]   = (_Float16)xr[i + j];
                int n  = i + j + 1;
                bsh[j] = (_Float16)(n < L_ ? xr[n] : 0.f);
            }
            *(f16x8*)(xh0 + (size_t)r * LP + i) = a;
            *(f16x8*)(xh1 + (size_t)r * LP + i) = bsh;
        }
        // zero the row pads [L_, LP)
        if (tid < 16) {
            f16x8 z;
            #pragma unroll
            for (int j = 0; j < 8; ++j) z[j] = (_Float16)0.f;
            *(f16x8*)(xh0  + (size_t)r * LP + L_ + tid * 8) = z;
            *(f16x8*)(xh1  + (size_t)r * LP + L_ + tid * 8) = z;
            *(f16x8*)(invh + (size_t)r * LP + L_ + tid * 8) = z;
        }

        // window inverse norms via sliding sum -> f16 (stride LP)
        _Float16* ivp = invh + (size_t)r * LP;
        const int w0 = tid * 8;
        float ss = 0.f;
        if (w0 < W_) {
            #pragma unroll
            for (int j = 0; j < S_; ++j) { float v = xr[w0 + j]; ss += v * v; }
        }
        #pragma unroll
        for (int u = 0; u < 8; ++u) {
            int w = w0 + u;
            float o = 0.f;
            if (u > 0 && w < W_)
                ss += xr[w + 63] * xr[w + 63] - xr[w - 1] * xr[w - 1];
            if (w < W_) o = 0.125f / fmaxf(sqrtf(ss), 1e-8f);
            if (w < L_) ivp[w] = (_Float16)o;
        }
        if (r < 64) out[r * 256 + tid] = 0.f;   // zero output
    }
}

// ---- main: B-register-resident streaming MFMA + relu + max ----
// grid (4 mh, 4 kg, 32 b) = 512 blocks (2/CU), 256 threads = 4 waves.
// Wave: 32 cols (colg = kg*4+wv) x FULL K=512, B held in 128 VGPRs the whole
// kernel; loops 8 window-tiles of 64. Per step: 2 A loads (L1-hot) + 2 MFMAs.
// A ring: 8 slots, prefetch distance 3 (3 mod 4 != 0 -> no slot collision;
// 64 slot-writes per tile, 64%8==0 -> phase-aligned across tiles).
// launch_bounds WITHOUT min-waves: allocator gets 512 unified regs, ~230 used
// -> no spill, HW occupancy still 2 waves/SIMD (512/230 = 2).
struct IvT { _Float16 v[8][2]; };

__global__ __launch_bounds__(256)
void mcs_k(const _Float16* __restrict__ Bp, const _Float16* __restrict__ xh0,
           const _Float16* __restrict__ xh1, const _Float16* __restrict__ invh,
           float* __restrict__ out) {
    const int mh  = blockIdx.x;          // window quarter (512 windows)
    const int kg  = blockIdx.y;          // col group-of-128
    const int b   = blockIdx.z;
    const int tid = threadIdx.x;
    const int lane = tid & 63;
    const int wv   = tid >> 6;
    const int colg = kg * 4 + wv;        // col group-of-32
    const int l31  = lane & 31;
    const int lh   = lane >> 5;
    const int par  = l31 & 1;
    const int W0   = mh * 512;

    const _Float16* xb  = (par ? xh1 - 1 : xh0) + (size_t)(b * C_) * LP;
    const _Float16* ivb = invh + (size_t)(b * C_) * LP;

    // B: full-K register-resident (32 frags = 128 VGPRs)
    f16x8 Breg[32];
    {
        const f16x8* Bq = (const f16x8*)Bp + colg * 64 + lane;
        #pragma unroll
        for (int s = 0; s < 32; ++s) Breg[s] = Bq[s * 16 * 64];
    }

    f16x8u Ar[8];           // A-frag ring, prefetch distance 3
    auto issueA = [&](int t, int s, int mt, int slot) {
        int c = s >> 2, ks = s & 3;
        int p = W0 + t * 64 + mt * 32 + l31 + ks * 16 + lh * 8;  // pad-safe
        Ar[slot] = *(const f16x8u*)(xb + c * LP + p);
    };
    auto loadIv = [&](int t) -> IvT {
        IvT r;
        int tc = t < 8 ? t : 0;          // tile-8 prefetch: dummy valid addr
        #pragma unroll
        for (int c = 0; c < 8; ++c) {
            r.v[c][0] = ivb[c * LP + W0 + tc * 64 + l31];
            r.v[c][1] = ivb[c * LP + W0 + tc * 64 + 32 + l31];
        }
        return r;
    };

    // prolog: fill ring with flat steps 0..2 of tile 0; iv for tile 0
    #pragma unroll
    for (int s = 0; s < 3; ++s) { issueA(0, s, 0, (s * 2) & 7); issueA(0, s, 1, (s * 2 + 1) & 7); }
    IvT ivA = loadIv(0), ivB;

    float mx = 0.f;
    f32x16 acc0, acc1;

    #pragma unroll 1
    for (int tp = 0; tp < 4; ++tp) {
        #pragma unroll
        for (int hf = 0; hf < 2; ++hf) {
            const int t = tp * 2 + hf;
            #pragma unroll
            for (int r = 0; r < 16; ++r) { acc0[r] = 0.f; acc1[r] = 0.f; }
            #pragma unroll
            for (int s = 0; s < 32; ++s) {
                int ps = s + 3;                       // prefetch 3 steps ahead
                int pt = t + (ps >> 5), pss = ps & 31;  // t=7 tail -> pad, safe
                issueA(pt, pss, 0, (ps * 2) & 7);
                issueA(pt, pss, 1, (ps * 2 + 1) & 7);
                if (s == 8) { if (hf) ivA = loadIv(t + 1); else ivB = loadIv(t + 1); }
                const IvT& iv = hf ? ivB : ivA;
                int c = s >> 2;
                f16x8 af0 = (f16x8)Ar[(s * 2) & 7] * iv.v[c][0];
                f16x8 af1 = (f16x8)Ar[(s * 2 + 1) & 7] * iv.v[c][1];
                acc0 = __builtin_amdgcn_mfma_f32_32x32x16_f16(af0, Breg[s], acc0, 0, 0, 0);
                acc1 = __builtin_amdgcn_mfma_f32_32x32x16_f16(af1, Breg[s], acc1, 0, 0, 0);
            }
            // fold tile max (relu floor 0; invalid windows exactly 0)
            #pragma unroll
            for (int r = 0; r < 16; ++r) mx = fmaxf(mx, fmaxf(acc0[r], acc1[r]));
        }
    }

    // 32x32 C/D: col = lane&31; lane and lane^32 hold different window rows
    mx = fmaxf(mx, __shfl_xor(mx, 32));
    if (lane < 32)
        atomicMax((unsigned int*)(out + b * K_ + colg * 32 + l31),
                  __float_as_uint(mx));
}

extern "C" void kernel_launch(void* const* d_in, const int* in_sizes, int n_in,
                              void* d_out, int out_size, void* d_ws, size_t ws_size,
                              hipStream_t stream) {
    const float* x  = (const float*)d_in[0];   // (32, 8, 2048) fp32
    const float* sh = (const float*)d_in[1];   // (8, 512, 64) fp32
    float* out = (float*)d_out;                // (32, 1, 512) fp32

    char* ws = (char*)d_ws;
    const size_t xhN = (size_t)B_ * C_ * LP * sizeof(_Float16);  // 1.09 MB
    _Float16* Bp   = (_Float16*)ws;                              // 512 KB
    _Float16* xh0  = (_Float16*)(ws + (512 << 10));
    _Float16* xh1  = (_Float16*)(ws + (512 << 10) + xhN);
    _Float16* invh = (_Float16*)(ws + (512 << 10) + 2 * xhN);

    prep_k<<<dim3(384), dim3(256), 0, stream>>>(x, sh, Bp, xh0, xh1, invh, out);
    mcs_k<<<dim3(4, 4, B_), dim3(256), 0, stream>>>(Bp, xh0, xh1, invh, out);
}